// Round 17
// baseline (123.744 us; speedup 1.0000x reference)
//
#include <hip/hip_runtime.h>
#include <math.h>

#define B 8
#define T 128
#define NKEY 127   // t-1
#define NPAD 128   // padded key count (score row 127 forced to prob 0)
#define KDIM 64    // Q_DIM == KV_DIM
#define NH 4       // heads
#define CH 256     // NH*KDIM output channels

typedef _Float16 half8v __attribute__((ext_vector_type(8)));  // 8 fp16 (4 VGPRs)
typedef float floatx4 __attribute__((ext_vector_type(4)));    // MFMA C/D

// tanh(x) = 1 - 2/(e^{2x}+1). Saturates correctly at +/-inf, no clamp needed.
__device__ __forceinline__ float fast_tanh(float x) {
    float e = __expf(2.f * x);
    float r = __builtin_amdgcn_rcpf(e + 1.f);
    return fmaf(-2.f, r, 1.f);
}

// 8x float -> fp16 RNE. Verified (R15/R17/R23 pass): absmax <= 9.77e-4.
__device__ __forceinline__ half8v cvt8_rne(const float4& a, const float4& b) {
    half8v h;
    h[0] = (_Float16)a.x; h[1] = (_Float16)a.y;
    h[2] = (_Float16)a.z; h[3] = (_Float16)a.w;
    h[4] = (_Float16)b.x; h[5] = (_Float16)b.y;
    h[6] = (_Float16)b.z; h[7] = (_Float16)b.w;
    return h;
}

// R24: ZERO-BARRIER restructure. Ledger of falsified theories: occupancy
// (R9/R10/R16), epilogue VALU (R18), staging latency (R19), score ILP (R20),
// memory transactions (R21), setprio (R22), code size (R23, weak +1us).
// Last untouched structural element: __syncthreads and the cross-wave kv
// sharing that forces it. The barrier emits s_waitcnt vmcnt(0) lgkmcnt(0)
// (drains ALL in-flight memory ops of every wave) and locks 4 waves x 1024
// blocks into phase-lockstep. Removal: each wave is fully self-contained --
//  * B-fragments loaded DIRECTLY from global per-nt (the staging pattern IS
//    the fragment pattern; same addresses, L2-hot from 4x block-level reuse)
//  * qb: wave h computes its own 64 channels into qb_lds[h] (wave-private)
//  * Phase B: R15-verified global column reads (fp32 -> numerics improve)
//  * p_lds/wkv_lds/Phase C: already wave-local in the champion
// LDS 37 KB -> 4 KB. No drain, no lockstep: 4096 independent waves drifting
// through different phases = the TLP overlap this kernel never had.
// All per-value math identical to the R23 champion (fast_tanh epilogue).
__global__ __launch_bounds__(256, 2)
void attn_kernel(const float* __restrict__ q_x,   // (B,T,64)
                 const float* __restrict__ kv_x,  // (B,T,127,64)
                 const float* __restrict__ Wk,    // (256,64)
                 const float* __restrict__ Wq,    // (256,64)
                 const float* __restrict__ Wv,    // (256,64)
                 const float* __restrict__ bias,  // (64,)
                 const float* __restrict__ Ws,    // (1,64)
                 const float* __restrict__ bs,    // (1,) -- cancels in softmax
                 float* __restrict__ out)         // (B,T,256)
{
    __shared__ float qb_lds[NH][64];                  // 1 KB: per-head query+bias
    __shared__ float p_lds[NH][NPAD];                 // 2 KB: scores then probs
    __shared__ __align__(16) float wkv_lds[NH][KDIM]; // 1 KB -> total 4 KB

    const int bt   = blockIdx.x;
    const int tid  = threadIdx.x;
    const int h    = tid >> 6;    // wave index == head index
    const int lane = tid & 63;
    const int col  = lane & 15;   // MFMA n/m lane index
    const int quad = lane >> 4;   // MFMA k-group / row-group

    const float* __restrict__ kvg = kv_x + (size_t)bt * NKEY * KDIM;

    // ---- qb: wave h computes its own 64 channels (c = h*64 + lane) ----
    // qb_lds[h] is written and later read ONLY by wave h (DS in-order).
    {
        const float4* Wq4 = (const float4*)(Wq + (size_t)tid * KDIM);
        const float4* q4g = (const float4*)(q_x + (size_t)bt * KDIM);
        float4 qa = {0.f, 0.f, 0.f, 0.f};
        #pragma unroll 4
        for (int i = 0; i < 16; ++i) {
            float4 w = Wq4[i];
            float4 q4 = q4g[i];
            qa.x = fmaf(q4.x, w.x, qa.x);
            qa.y = fmaf(q4.y, w.y, qa.y);
            qa.z = fmaf(q4.z, w.z, qa.z);
            qa.w = fmaf(q4.w, w.w, qa.w);
        }
        qb_lds[h][lane] = (qa.x + qa.y) + (qa.z + qa.w) + bias[lane];
    }

    // ---- A-fragments: Wk rows of this head, fp16 RNE ----
    // lane holds Wk[h*64 + jt*16 + col][ks*32 + quad*8 + j]
    half8v ah[4][2];
    #pragma unroll
    for (int jt = 0; jt < 4; ++jt)
        #pragma unroll
        for (int ks = 0; ks < 2; ++ks) {
            const float* wrow = Wk + (size_t)(h * 64 + jt * 16 + col) * KDIM
                                   + ks * 32 + quad * 8;
            float4 a = *(const float4*)wrow;
            float4 b = *(const float4*)(wrow + 4);
            ah[jt][ks] = cvt8_rne(a, b);
        }

    // ---- per-lane qb / ws for epilogue: j = jt*16 + quad*4 + r ----
    // qb_lds[h] read by same wave that wrote it: DS in-order, no barrier.
    float qbv[4][4], wsv[4][4];
    #pragma unroll
    for (int jt = 0; jt < 4; ++jt)
        #pragma unroll
        for (int r = 0; r < 4; ++r) {
            int j = jt * 16 + quad * 4 + r;
            qbv[jt][r] = qb_lds[h][j];
            wsv[jt][r] = Ws[j];
        }

    // ---- scores: 8 n-tiles; B-fragments loaded DIRECT from global ----
    // Fragment = kv[nt*16 + col][{quad*8..+7, 32+quad*8..+7}]: exactly the
    // old staging addresses (L2-hot: 4 waves/block read the same lines).
    #pragma unroll 2
    for (int nt = 0; nt < 8; ++nt) {
        const int n = nt * 16 + col;
        float4 f0 = {0.f,0.f,0.f,0.f}, f1 = {0.f,0.f,0.f,0.f};
        float4 f2 = {0.f,0.f,0.f,0.f}, f3 = {0.f,0.f,0.f,0.f};
        if (n < NKEY) {
            const float* p = kvg + (size_t)n * KDIM + quad * 8;
            f0 = *(const float4*)p;          // ks=0: k = quad*8 + 0..3
            f1 = *(const float4*)(p + 4);    //        k = quad*8 + 4..7
            f2 = *(const float4*)(p + 32);   // ks=1: k = 32 + quad*8 + 0..3
            f3 = *(const float4*)(p + 36);
        }
        half8v b0 = cvt8_rne(f0, f1);
        half8v b1 = cvt8_rne(f2, f3);

        floatx4 acc[4];
        #pragma unroll
        for (int jt = 0; jt < 4; ++jt) {
            floatx4 c = {0.f, 0.f, 0.f, 0.f};
            c = __builtin_amdgcn_mfma_f32_16x16x32_f16(ah[jt][0], b0, c, 0, 0, 0);
            c = __builtin_amdgcn_mfma_f32_16x16x32_f16(ah[jt][1], b1, c, 0, 0, 0);
            acc[jt] = c;
        }

        // epilogue: score[n] = sum_j tanh(key + qb[j]) * ws[j]
        // D layout: col = lane&15 = n in tile, row = quad*4 + r = j in jt
        float partial = 0.f;
        #pragma unroll
        for (int jt = 0; jt < 4; ++jt)
            #pragma unroll
            for (int r = 0; r < 4; ++r)
                partial = fmaf(fast_tanh(acc[jt][r] + qbv[jt][r]), wsv[jt][r], partial);
        partial += __shfl_xor(partial, 16, 64);   // reduce across quads (same col)
        partial += __shfl_xor(partial, 32, 64);
        if (lane < 16) p_lds[h][nt * 16 + lane] = partial;
    }
    // no barrier: wave h is sole writer+reader of p_lds[h][*] (DS in-order)

    // ---- softmax over the 127 real keys (2 scores per lane) ----
    float invl;
    {
        float s_a = p_lds[h][lane];
        float s_b = p_lds[h][64 + lane];
        if (lane == 63) s_b = -1e30f;          // mask pad row 127
        float mx = fmaxf(s_a, s_b);
        #pragma unroll
        for (int off = 32; off > 0; off >>= 1)
            mx = fmaxf(mx, __shfl_xor(mx, off, 64));
        float pa = __expf(s_a - mx);
        float pb = __expf(s_b - mx);           // lane 63 -> 0
        float ls = pa + pb;
        #pragma unroll
        for (int off = 32; off > 0; off >>= 1)
            ls += __shfl_xor(ls, off, 64);
        invl = 1.f / ls;
        p_lds[h][lane]      = pa;              // unnormalized probs
        p_lds[h][64 + lane] = pb;              // p_lds[h][127] = 0 masks pad
    }

    // ---- Phase B: wkv[h][lane] = (sum_n p[n] * kv[n][lane]) / l ----
    // R15-verified global column reads (L2-hot), probs broadcast from LDS.
    {
        const float* kvl = kvg + lane;
        float w0 = 0.f, w1 = 0.f, w2 = 0.f, w3 = 0.f;
        #pragma unroll 4
        for (int n4 = 0; n4 < NPAD; n4 += 4) {
            float4 p4 = *(const float4*)&p_lds[h][n4];       // uniform broadcast
            const int n3 = (n4 + 3 < NKEY) ? (n4 + 3) : 0;   // p4.w==0 there
            w0 = fmaf(p4.x, kvl[(size_t)(n4 + 0) * KDIM], w0);
            w1 = fmaf(p4.y, kvl[(size_t)(n4 + 1) * KDIM], w1);
            w2 = fmaf(p4.z, kvl[(size_t)(n4 + 2) * KDIM], w2);
            w3 = fmaf(p4.w, kvl[(size_t)n3 * KDIM], w3);
        }
        wkv_lds[h][lane] = ((w0 + w1) + (w2 + w3)) * invl;
    }
    // no barrier: wkv_lds[h] written and read only by wave h (DS in-order)

    // ---- Phase C: out[j] = wkv[h,:] . Wv[j,:] (wave-local) ----
    {
        const float4* Wv4 = (const float4*)(Wv + (size_t)tid * KDIM);
        const float4* wv_row = (const float4*)wkv_lds[h];
        float4 oa = {0.f, 0.f, 0.f, 0.f};
        #pragma unroll 4
        for (int i = 0; i < 16; ++i) {
            float4 w = Wv4[i];
            float4 c = wv_row[i];                        // broadcast
            oa.x = fmaf(c.x, w.x, oa.x);
            oa.y = fmaf(c.y, w.y, oa.y);
            oa.z = fmaf(c.z, w.z, oa.z);
            oa.w = fmaf(c.w, w.w, oa.w);
        }
        out[(size_t)bt * CH + tid] = (oa.x + oa.y) + (oa.z + oa.w);
    }
}

extern "C" void kernel_launch(void* const* d_in, const int* in_sizes, int n_in,
                              void* d_out, int out_size, void* d_ws, size_t ws_size,
                              hipStream_t stream) {
    const float* q_x  = (const float*)d_in[0];
    const float* kv_x = (const float*)d_in[1];
    const float* Wk   = (const float*)d_in[2];
    const float* Wq   = (const float*)d_in[3];
    const float* Wv   = (const float*)d_in[4];
    const float* bias = (const float*)d_in[5];
    const float* Ws   = (const float*)d_in[6];
    const float* bs   = (const float*)d_in[7];
    float* out = (float*)d_out;

    attn_kernel<<<dim3(B * T), dim3(256), 0, stream>>>(
        q_x, kv_x, Wk, Wq, Wv, bias, Ws, bs, out);
}